// Round 7
// baseline (174.382 us; speedup 1.0000x reference)
//
#include <hip/hip_runtime.h>

#define N_NODES 100000
#define N_EDGES 1600000
#define DIM     64
#define HID     256
#define BN_EPS  1e-5f

// counting-sort parameters
#define NBUCK   391            // ceil(100000/256) buckets of 256 nodes
#define RSTRIDE 392            // runoff row stride (NBUCK + 1 for chunk total)
#define SCHUNK  3125           // edges per kA_scatter block
#define SBLK    512            // 512 * 3125 = 1,600,000 exactly
#define MAXB    6144           // max edges per bucket (mean 4096, sd 64 -> +32 sd)

// MLP parameters
#define XBROWS  100032         // padded xb rows
#define NT      391            // ceil(100032/256) tiles of 256 rows
#define MLPGRID 256            // 1 block/CU (LDS-forced); grid == CU count
#define MAXIT   2              // ceil(NT/MLPGRID)

typedef short bf16x8 __attribute__((ext_vector_type(8)));
typedef float f32x4  __attribute__((ext_vector_type(4)));

// ws layout (4-byte units):
//   stats   float[128]         @ 0        (sum[64], sumsq[64])   [zeroed by kA blk34]
//   bar     int[128]           @ 128      (grid barrier)         [zeroed by kA blk34]
//   runoff  int[512*392]       @ 256      (200704; dead after kB_fused -> dump)
//   w1t_g   bf16[256*64]       @ 200960   (8192 ints) [n][k] chunk-swizzled
//   w2t_g   bf16[64*256]       @ 209152   (8192 ints) [d][k2] chunk-swizzled
//   xb      bf16[100032*64]    @ 217344   (3201024 ints, 16B aligned)
//   ebuf    u32[1600000]       @ 3418368
//   hb      bf16[100000*64]    @ 5018368  (3200000 ints) h in bf16 row-major

// native bf16 convert (RNE): compiler emits v_cvt_pk_bf16_f32 for adjacent pairs
__device__ __forceinline__ unsigned short f2bf(float x) {
    union { __bf16 b; unsigned short u; } cv;
    cv.b = (__bf16)x;
    return cv.u;
}
__device__ __forceinline__ unsigned pk2(float a, float b) {
    return (unsigned)f2bf(a) | ((unsigned)f2bf(b) << 16);
}

#define WAITV(N) asm volatile("s_waitcnt vmcnt(" #N ")" ::: "memory")

// issue 2x global_load_lds(16B) staging 16 rows (2048 B) into per-wave LDS buffer.
__device__ __forceinline__ void stage_issue(const unsigned short* gsrc,
                                            unsigned short* ldst) {
    __builtin_amdgcn_global_load_lds(
        (const __attribute__((address_space(1))) void*)gsrc,
        (__attribute__((address_space(3))) void*)ldst, 16, 0, 0);
    __builtin_amdgcn_global_load_lds(
        (const __attribute__((address_space(1))) void*)(gsrc + 512),
        (__attribute__((address_space(3))) void*)(ldst + 512), 16, 0, 0);
}

// ---------------------------------------------------------------------------
// Pass A: per-chunk LDS counting sort by coarse bucket (dst>>8)
// + fused prep epilogue: h->bf16 hb (all blocks), weight transpose+swizzle
//   (blocks 0..33, 1 elem/thread), xb pad zero, stats/bar zero (block 34).
// ---------------------------------------------------------------------------
__global__ __launch_bounds__(1024) void kA_scatter(const int* __restrict__ src,
                                                   const int* __restrict__ dst,
                                                   const float* __restrict__ h,
                                                   const float* __restrict__ W1,
                                                   const float* __restrict__ W2,
                                                   unsigned int* __restrict__ ebuf,
                                                   int* __restrict__ runoff,
                                                   unsigned short* __restrict__ w1t,
                                                   unsigned short* __restrict__ w2t,
                                                   unsigned short* __restrict__ xb,
                                                   unsigned short* __restrict__ hb,
                                                   int* __restrict__ statsbar) {
    __shared__ int hist[NBUCK];
    __shared__ int ebase[NBUCK];
    __shared__ int sc[512];
    __shared__ unsigned int stage[SCHUNK];
    const int t = threadIdx.x;
    const int e0 = blockIdx.x * SCHUNK;
    const int n = SCHUNK;                         // exact partition

    for (int i = t; i < NBUCK; i += 1024) hist[i] = 0;
    __syncthreads();
    for (int i = t; i < n; i += 1024)
        atomicAdd(&hist[dst[e0 + i] >> 8], 1);    // int LDS atomic: native ds op
    __syncthreads();

    if (t < 512) sc[t] = (t < NBUCK) ? hist[t] : 0;
    __syncthreads();
    for (int off = 1; off < 512; off <<= 1) {
        int add = (t < 512 && t >= off) ? sc[t - off] : 0;
        __syncthreads();
        if (t < 512) sc[t] += add;
        __syncthreads();
    }
    if (t < NBUCK) {
        int ex = sc[t] - hist[t];
        ebase[t] = ex;
        runoff[blockIdx.x * RSTRIDE + t] = ex;
    }
    if (t == 0) runoff[blockIdx.x * RSTRIDE + NBUCK] = n;
    if (t < NBUCK) hist[t] = 0;
    __syncthreads();

    for (int i = t; i < n; i += 1024) {
        int d = dst[e0 + i];
        int s = src[e0 + i];
        int b = d >> 8;
        int r = atomicAdd(&hist[b], 1);
        stage[ebase[b] + r] = ((unsigned int)s << 8) | (unsigned int)(d & 255);
    }
    __syncthreads();
    for (int i = t; i < n; i += 1024)
        ebuf[e0 + i] = stage[i];

    // ---- fused prep epilogue (no LDS, no barriers needed) ----
    for (int i = blockIdx.x * 1024 + t; i < 800000; i += SBLK * 1024) {
        int e = i * 8;
        float4 f0 = *(const float4*)&h[e];
        float4 f1 = *(const float4*)&h[e + 4];
        uint4 o;
        o.x = pk2(f0.x, f0.y);
        o.y = pk2(f0.z, f0.w);
        o.z = pk2(f1.x, f1.y);
        o.w = pk2(f1.z, f1.w);
        *(uint4*)&hb[e] = o;
    }
    int id = blockIdx.x * 1024 + t;
    if (id < 16384) {                            // w1t: n*64+k
        int nn = id >> 6, k = id & 63;
        int dstp = (nn << 6) + ((((k >> 3) ^ (nn & 7))) << 3) + (k & 7);
        w1t[dstp] = f2bf(W1[k * 256 + nn]);
    } else if (id < 32768) {                     // w2t: d*256+k2
        int i2 = id - 16384;
        int d = i2 >> 8, k2 = i2 & 255;
        int dstp = (d << 8) + ((((k2 >> 3) ^ (d & 7))) << 3) + (k2 & 7);
        w2t[dstp] = f2bf(W2[k2 * 64 + d]);
    } else if (id < 34816) {                     // zero 32 pad rows of xb
        xb[100000 * 64 + (id - 32768)] = 0;
    }
    if (blockIdx.x == 34 && t < 256) statsbar[t] = 0;
}

// ---------------------------------------------------------------------------
// Pass B (fused, register-accumulate): one block per bucket.
// 1) 2-threads-per-run copy of bucket edges -> stage2 (LDS) + degree histogram
// 2) per-node offsets via LDS scan; sort src ids into sout (int LDS atomics)
// 3) 8-lane group per node: walk contiguous sout segment with 1-deep
//    prefetch pipeline, register-accumulate, emit xb row (swizzled bf16).
// ---------------------------------------------------------------------------
__global__ __launch_bounds__(1024) void kB_fused(const unsigned int* __restrict__ ebuf,
                                                 const int* __restrict__ runoff,
                                                 const unsigned short* __restrict__ hb,
                                                 unsigned short* __restrict__ xb) {
    __shared__ int runstart_s[SBLK];
    __shared__ int sc[SBLK];
    __shared__ int cnt[256];
    __shared__ int off[256];
    __shared__ unsigned int stage2[MAXB];
    __shared__ unsigned int sout[MAXB];
    const int t = threadIdx.x;
    const int b = blockIdx.x;

    int rl = 0;
    if (t < SBLK) {
        int s = runoff[t * RSTRIDE + b];
        int e = runoff[t * RSTRIDE + b + 1];
        runstart_s[t] = t * SCHUNK + s;
        rl = e - s;
        sc[t] = rl;
    }
    if (t < 256) cnt[t] = 0;
    __syncthreads();
    for (int o = 1; o < SBLK; o <<= 1) {
        int add = (t < SBLK && t >= o) ? sc[t - o] : 0;
        __syncthreads();
        if (t < SBLK) sc[t] += add;
        __syncthreads();
    }
    const int total = min(sc[SBLK - 1], MAXB);
    __syncthreads();

    // copy into LDS: two threads per run (front half / back half) + histogram
    {
        const int r = t & 511;
        const int hf = t >> 9;
        int prev = (r == 0) ? 0 : sc[r - 1];
        int rlr = sc[r] - prev;
        int h0 = (rlr + 1) >> 1;
        int st = hf ? h0 : 0;
        int en = hf ? rlr : h0;
        int rs0 = runstart_s[r];
        for (int k = st; k < en; ++k) {
            int pos = prev + k;
            if (pos >= MAXB) break;
            unsigned int v = ebuf[rs0 + k];
            stage2[pos] = v;
            atomicAdd(&cnt[v & 255u], 1);
        }
    }
    __syncthreads();

    // per-node exclusive offsets within the bucket
    int c0 = (t < 256) ? cnt[t] : 0;
    if (t < 256) sc[t] = c0;
    __syncthreads();
    for (int o = 1; o < 256; o <<= 1) {
        int add = (t < 256 && t >= o) ? sc[t - o] : 0;
        __syncthreads();
        if (t < 256) sc[t] += add;
        __syncthreads();
    }
    if (t < 256) { off[t] = sc[t] - c0; cnt[t] = 0; }
    __syncthreads();

    // sort src ids by node into sout (contiguous per-node segments)
    for (int idx = t; idx < total; idx += 1024) {
        unsigned int v = stage2[idx];
        int node = (int)(v & 255u);
        int r = atomicAdd(&cnt[node], 1);
        sout[off[node] + r] = v >> 8;
    }
    __syncthreads();

    // aggregate: 8-lane group per node; lane c covers dims c*8..c*8+7.
    const int g = t >> 3, c = t & 7;
    const unsigned short* hc = hb + c * 8;
    const int gn0 = b * 256;
#pragma unroll
    for (int pass = 0; pass < 2; ++pass) {
        int nloc = pass * 128 + g;
        int gnode = gn0 + nloc;
        if (gnode >= N_NODES) continue;
        const int o0 = off[nloc];
        const int dg = cnt[nloc];
        float a0 = 0.f, a1 = 0.f, a2 = 0.f, a3 = 0.f;
        float a4 = 0.f, a5 = 0.f, a6 = 0.f, a7 = 0.f;
        const int npair = dg >> 1;
        uint4 p0, p1;
        if (npair > 0) {
            int i0 = (int)sout[o0];
            int i1 = (int)sout[o0 + 1];
            p0 = *(const uint4*)&hc[(size_t)i0 * 64];
            p1 = *(const uint4*)&hc[(size_t)i1 * 64];
        }
        for (int q = 0; q < npair; ++q) {
            uint4 c0v = p0, c1v = p1;
            int j2 = (q + 1) * 2;
            if (q + 1 < npair) {
                int ia = (int)sout[o0 + j2];
                int ib = (int)sout[o0 + j2 + 1];
                p0 = *(const uint4*)&hc[(size_t)ia * 64];
                p1 = *(const uint4*)&hc[(size_t)ib * 64];
            }
            a0 += __uint_as_float(c0v.x << 16); a1 += __uint_as_float(c0v.x & 0xffff0000u);
            a2 += __uint_as_float(c0v.y << 16); a3 += __uint_as_float(c0v.y & 0xffff0000u);
            a4 += __uint_as_float(c0v.z << 16); a5 += __uint_as_float(c0v.z & 0xffff0000u);
            a6 += __uint_as_float(c0v.w << 16); a7 += __uint_as_float(c0v.w & 0xffff0000u);
            a0 += __uint_as_float(c1v.x << 16); a1 += __uint_as_float(c1v.x & 0xffff0000u);
            a2 += __uint_as_float(c1v.y << 16); a3 += __uint_as_float(c1v.y & 0xffff0000u);
            a4 += __uint_as_float(c1v.z << 16); a5 += __uint_as_float(c1v.z & 0xffff0000u);
            a6 += __uint_as_float(c1v.w << 16); a7 += __uint_as_float(c1v.w & 0xffff0000u);
        }
        if (dg & 1) {
            int il = (int)sout[o0 + dg - 1];
            uint4 v0 = *(const uint4*)&hc[(size_t)il * 64];
            a0 += __uint_as_float(v0.x << 16); a1 += __uint_as_float(v0.x & 0xffff0000u);
            a2 += __uint_as_float(v0.y << 16); a3 += __uint_as_float(v0.y & 0xffff0000u);
            a4 += __uint_as_float(v0.z << 16); a5 += __uint_as_float(v0.z & 0xffff0000u);
            a6 += __uint_as_float(v0.w << 16); a7 += __uint_as_float(v0.w & 0xffff0000u);
        }
        const float inv = 1.0f / (float)max(dg, 1);
        uint4 ov = *(const uint4*)&hc[(size_t)gnode * 64];
        float x0 = fmaf(a0, inv, __uint_as_float(ov.x << 16));
        float x1 = fmaf(a1, inv, __uint_as_float(ov.x & 0xffff0000u));
        float x2 = fmaf(a2, inv, __uint_as_float(ov.y << 16));
        float x3 = fmaf(a3, inv, __uint_as_float(ov.y & 0xffff0000u));
        float x4 = fmaf(a4, inv, __uint_as_float(ov.z << 16));
        float x5 = fmaf(a5, inv, __uint_as_float(ov.z & 0xffff0000u));
        float x6 = fmaf(a6, inv, __uint_as_float(ov.w << 16));
        float x7 = fmaf(a7, inv, __uint_as_float(ov.w & 0xffff0000u));
        uint4 o;
        o.x = pk2(x0, x1);
        o.y = pk2(x2, x3);
        o.z = pk2(x4, x5);
        o.w = pk2(x6, x7);
        *(uint4*)&xb[(size_t)gnode * 64 + ((c ^ (gnode & 7)) << 3)] = o;
    }
}

// ---------------------------------------------------------------------------
// Fused MLP core (structure verified at r3)
// ---------------------------------------------------------------------------
__device__ __forceinline__ void mlp_tile(const unsigned short* sXw,
                                         const unsigned short* sW1,
                                         const unsigned short* sW2,
                                         unsigned short* sHw,
                                         const float* sB1,
                                         int l15, int g4, int s7,
                                         f32x4 oacc[4]) {
    bf16x8 xf0 = *(const bf16x8*)&sXw[l15 * 64 + ((g4 ^ s7) << 3)];
    bf16x8 xf1 = *(const bf16x8*)&sXw[l15 * 64 + (((g4 + 4) ^ s7) << 3)];
#pragma unroll
    for (int dt = 0; dt < 4; ++dt) oacc[dt] = (f32x4){0.f, 0.f, 0.f, 0.f};

#pragma unroll
    for (int p = 0; p < 4; ++p) {
#pragma unroll
        for (int nt2 = 0; nt2 < 4; ++nt2) {
            const int n0 = p * 64 + nt2 * 16;
            f32x4 hacc = (f32x4){0.f, 0.f, 0.f, 0.f};
            bf16x8 wf0 = *(const bf16x8*)&sW1[(n0 + l15) * 64 + ((g4 ^ s7) << 3)];
            bf16x8 wf1 = *(const bf16x8*)&sW1[(n0 + l15) * 64 + (((g4 + 4) ^ s7) << 3)];
            hacc = __builtin_amdgcn_mfma_f32_16x16x32_bf16(wf0, xf0, hacc, 0, 0, 0);
            hacc = __builtin_amdgcn_mfma_f32_16x16x32_bf16(wf1, xf1, hacc, 0, 0, 0);
            float4 bq = *(const float4*)&sB1[n0 + g4 * 4];
            unsigned plo = pk2(fmaxf(hacc[0] + bq.x, 0.f),
                               fmaxf(hacc[1] + bq.y, 0.f));
            unsigned phi = pk2(fmaxf(hacc[2] + bq.z, 0.f),
                               fmaxf(hacc[3] + bq.w, 0.f));
            int qh = nt2 * 2 + (g4 >> 1);
            uint2 pk = {plo, phi};
            *(uint2*)&sHw[l15 * 64 + ((qh ^ s7) << 3) + ((g4 & 1) << 2)] = pk;
        }
#pragma unroll
        for (int s2 = 0; s2 < 2; ++s2) {
            bf16x8 a2 = *(const bf16x8*)&sHw[l15 * 64 + (((s2 * 4 + g4) ^ s7) << 3)];
#pragma unroll
            for (int dt = 0; dt < 4; ++dt) {
                int q = p * 8 + s2 * 4 + g4;
                bf16x8 w2f = *(const bf16x8*)&sW2[(dt * 16 + l15) * 256 + ((q ^ s7) << 3)];
                oacc[dt] = __builtin_amdgcn_mfma_f32_16x16x32_bf16(a2, w2f, oacc[dt], 0, 0, 0);
            }
        }
    }
}

// single-pass MLP + BN (grid barrier; 256 blocks x 1024 thr = 1 block/CU,
// 16 waves/CU = 4 waves/SIMD for LDS/MFMA latency hiding).
// LDS: 32K sW1 + 32K sW2 + 32K sH + 32K sX + 1K sB1 = 129 KB.
__global__ __launch_bounds__(1024, 1) void k_mlpf(const unsigned short* __restrict__ xb,
                                                  const unsigned short* __restrict__ w1t,
                                                  const unsigned short* __restrict__ w2t,
                                                  const float* __restrict__ b1,
                                                  const float* __restrict__ b2,
                                                  const float* __restrict__ gamma,
                                                  const float* __restrict__ beta,
                                                  float* __restrict__ stats,
                                                  int* __restrict__ bar,
                                                  float* __restrict__ out,
                                                  float* __restrict__ dump) {
    __shared__ unsigned short sW1[256 * 64];
    __shared__ unsigned short sW2[64 * 256];
    __shared__ unsigned short sH[16][16 * 64];
    __shared__ unsigned short sX[16][16 * 64];
    __shared__ float sB1[256];
    const int t = threadIdx.x;
    const int lane = t & 63;
    const int w = t >> 6;                     // 0..15
    const int l15 = lane & 15;
    const int g4 = lane >> 4;
    const int s7 = l15 & 7;
    const int bid = blockIdx.x;

    for (int i = t; i < 2048; i += 1024)
        *(uint4*)&sW1[i * 8] = *(const uint4*)&w1t[i * 8];
    for (int i = t; i < 2048; i += 1024)
        *(uint4*)&sW2[i * 8] = *(const uint4*)&w2t[i * 8];
    if (t < 256) sB1[t] = b1[t];
    __syncthreads();

    float b2v[4];
#pragma unroll
    for (int dt = 0; dt < 4; ++dt) b2v[dt] = b2[dt * 16 + l15];

    float lsum[4] = {0.f, 0.f, 0.f, 0.f};
    float lsq[4]  = {0.f, 0.f, 0.f, 0.f};
    f32x4 osave[MAXIT][4];

#pragma unroll
    for (int it = 0; it < MAXIT; ++it) {
        int gp = bid + it * MLPGRID;
        int r0c = min(gp * 256 + w * 16, XBROWS - 16);
        stage_issue(xb + (size_t)r0c * 64 + lane * 8, &sX[w][0]);
        WAITV(0);
        __builtin_amdgcn_sched_barrier(0);
        const int row0 = gp * 256 + w * 16;
        if (gp < NT && row0 < XBROWS) {
            f32x4 oacc[4];
            mlp_tile(&sX[w][0], sW1, sW2, &sH[w][0], sB1, l15, g4, s7, oacc);
#pragma unroll
            for (int dt = 0; dt < 4; ++dt) {
#pragma unroll
                for (int r = 0; r < 4; ++r) {
                    float val = fmaxf(oacc[dt][r] + b2v[dt], 0.f);
                    osave[it][dt][r] = val;
                    int mabs = row0 + g4 * 4 + r;
                    if (mabs < N_NODES) {
                        lsum[dt] += val;
                        lsq[dt] += val * val;
                    }
                }
            }
        }
    }

    // block-level stats reduction (reuse sW1 memory: [1024][8] f32 = 32 KB)
    __syncthreads();
    float* sred = (float*)&sW1[0];
#pragma unroll
    for (int dt = 0; dt < 4; ++dt) {
        sred[t * 8 + dt] = lsum[dt];
        sred[t * 8 + 4 + dt] = lsq[dt];
    }
    __syncthreads();
    if (t < 128) {
        int issq = (t >= 64) ? 4 : 0;
        int d = t & 63;
        int dt = d >> 4, dl = d & 15;
        float acc = 0.f;
        for (int i = 0; i < 64; ++i) acc += sred[(dl + 16 * i) * 8 + issq + dt];
        atomicAdd(&stats[(issq ? 64 : 0) + d], acc);
    }

    // software grid barrier (all 256 blocks co-resident: 1 block/CU)
    __syncthreads();
    if (t == 0) {
        __hip_atomic_fetch_add(bar, 1, __ATOMIC_ACQ_REL, __HIP_MEMORY_SCOPE_AGENT);
        while (__hip_atomic_load(bar, __ATOMIC_ACQUIRE, __HIP_MEMORY_SCOPE_AGENT)
               < MLPGRID)
            __builtin_amdgcn_s_sleep(4);
    }
    __syncthreads();

    float scv[4], shv[4];
    const float inv_n = 1.0f / (float)N_NODES;
#pragma unroll
    for (int dt = 0; dt < 4; ++dt) {
        int d = dt * 16 + l15;
        float sm = __hip_atomic_load(&stats[d], __ATOMIC_RELAXED,
                                     __HIP_MEMORY_SCOPE_AGENT);
        float sq = __hip_atomic_load(&stats[64 + d], __ATOMIC_RELAXED,
                                     __HIP_MEMORY_SCOPE_AGENT);
        float m = sm * inv_n;
        float v = sq * inv_n - m * m;
        float sc = gamma[d] * rsqrtf(v + BN_EPS);
        scv[dt] = sc;
        shv[dt] = beta[d] - m * sc;
    }

#pragma unroll
    for (int it = 0; it < MAXIT; ++it) {
        int gp = bid + it * MLPGRID;
        const int row0 = gp * 256 + w * 16;
        if (gp >= NT || row0 >= XBROWS) continue;
        float* sHf = (float*)&sH[w][0];           // [8][64] f32 = 2048 B
#pragma unroll
        for (int hh = 0; hh < 2; ++hh) {
            asm volatile("" ::: "memory");
            if ((g4 >> 1) == hh) {
#pragma unroll
                for (int dt = 0; dt < 4; ++dt) {
#pragma unroll
                    for (int r = 0; r < 4; ++r) {
                        float val = fmaf(osave[it][dt][r], scv[dt], shv[dt]);
                        sHf[((g4 & 1) * 4 + r) * 64 + dt * 16 + l15] = val;
                    }
                }
            }
            asm volatile("" ::: "memory");
#pragma unroll
            for (int j = 0; j < 2; ++j) {
                int rl = j * 4 + (lane >> 4);
                int rg = row0 + hh * 8 + rl;
                float4 v = *(const float4*)&sHf[rl * 64 + (lane & 15) * 4];
                float* dstp = (rg < N_NODES)
                    ? &out[(size_t)rg * 64 + (lane & 15) * 4]
                    : &dump[lane * 4];
                *(float4*)dstp = v;
            }
        }
    }
}

extern "C" void kernel_launch(void* const* d_in, const int* in_sizes, int n_in,
                              void* d_out, int out_size, void* d_ws, size_t ws_size,
                              hipStream_t stream) {
    const float* h     = (const float*)d_in[0];
    const float* W1    = (const float*)d_in[1];
    const float* b1    = (const float*)d_in[2];
    const float* W2    = (const float*)d_in[3];
    const float* b2    = (const float*)d_in[4];
    const float* gamma = (const float*)d_in[5];
    const float* beta  = (const float*)d_in[6];
    const int*   src   = (const int*)d_in[7];
    const int*   dst   = (const int*)d_in[8];

    int* wsi = (int*)d_ws;
    float*          stats    = (float*)wsi;                        // 128
    int*            bar      = wsi + 128;                          // 128
    int*            statsbar = wsi;                                // 256 ints
    int*            runoff   = wsi + 256;                          // 200704
    float*          dump     = (float*)(wsi + 256);                // alias (dead)
    unsigned short* w1t      = (unsigned short*)(wsi + 200960);    // 8192 ints
    unsigned short* w2t      = (unsigned short*)(wsi + 209152);    // 8192 ints
    unsigned short* xb       = (unsigned short*)(wsi + 217344);    // 3201024 ints
    unsigned int*   ebuf     = (unsigned int*)(wsi + 3418368);     // 1600000
    unsigned short* hb       = (unsigned short*)(wsi + 5018368);   // 3200000 ints
    float*          out      = (float*)d_out;

    kA_scatter<<<SBLK, 1024, 0, stream>>>(src, dst, h, W1, W2, ebuf, runoff,
                                          w1t, w2t, xb, hb, statsbar);
    kB_fused<<<NBUCK, 1024, 0, stream>>>(ebuf, runoff, hb, xb);
    k_mlpf<<<MLPGRID, 1024, 0, stream>>>(xb, w1t, w2t, b1, b2, gamma, beta,
                                         stats, bar, out, dump);
}

// Round 8
// 172.858 us; speedup vs baseline: 1.0088x; 1.0088x over previous
//
#include <hip/hip_runtime.h>

#define N_NODES 100000
#define N_EDGES 1600000
#define DIM     64
#define HID     256
#define BN_EPS  1e-5f

// counting-sort parameters
#define NBUCK   391            // ceil(100000/256) buckets of 256 nodes
#define RSTRIDE 392            // runoff row stride (NBUCK + 1 for chunk total)
#define SCHUNK  3125           // edges per kA_scatter block
#define SBLK    512            // 512 * 3125 = 1,600,000 exactly
#define MAXB    6144           // max edges per bucket (mean 4096, sd 64 -> +32 sd)

// MLP parameters
#define XBROWS  100032         // padded xb rows
#define NT      391            // ceil(100032/256) tiles of 256 rows
#define MLPGRID 256            // 1 block/CU (LDS-forced); grid == CU count
#define MAXIT   2              // ceil(NT/MLPGRID)

typedef short bf16x8 __attribute__((ext_vector_type(8)));
typedef float f32x4  __attribute__((ext_vector_type(4)));

// ws layout (4-byte units):
//   stats   float[128]         @ 0        (sum[64], sumsq[64])   [zeroed by kA blk34]
//   bar     int[128]           @ 128      (grid barrier)         [zeroed by kA blk34]
//   runoff  int[512*392]       @ 256      (200704; dead after kB_fused -> dump)
//   w1t_g   bf16[256*64]       @ 200960   (8192 ints) [n][k] chunk-swizzled
//   w2t_g   bf16[64*256]       @ 209152   (8192 ints) [d][k2] chunk-swizzled
//   xb      bf16[100032*64]    @ 217344   (3201024 ints, 16B aligned)
//   ebuf    u32[1600000]       @ 3418368
//   hb      bf16[100000*64]    @ 5018368  (3200000 ints) h in bf16 row-major

// native bf16 convert (RNE): compiler emits v_cvt_pk_bf16_f32 for adjacent pairs
__device__ __forceinline__ unsigned short f2bf(float x) {
    union { __bf16 b; unsigned short u; } cv;
    cv.b = (__bf16)x;
    return cv.u;
}
__device__ __forceinline__ unsigned pk2(float a, float b) {
    return (unsigned)f2bf(a) | ((unsigned)f2bf(b) << 16);
}

#define WAITV(N) asm volatile("s_waitcnt vmcnt(" #N ")" ::: "memory")

// issue 2x global_load_lds(16B) staging 16 rows (2048 B) into per-wave LDS buffer.
__device__ __forceinline__ void stage_issue(const unsigned short* gsrc,
                                            unsigned short* ldst) {
    __builtin_amdgcn_global_load_lds(
        (const __attribute__((address_space(1))) void*)gsrc,
        (__attribute__((address_space(3))) void*)ldst, 16, 0, 0);
    __builtin_amdgcn_global_load_lds(
        (const __attribute__((address_space(1))) void*)(gsrc + 512),
        (__attribute__((address_space(3))) void*)(ldst + 512), 16, 0, 0);
}

// ---------------------------------------------------------------------------
// Pass A: per-chunk LDS counting sort by coarse bucket (dst>>8)
// + fused prep epilogue: h->bf16 hb (all blocks), weight transpose+swizzle
//   (blocks 0..33, 1 elem/thread), xb pad zero, stats/bar zero (block 34).
// ---------------------------------------------------------------------------
__global__ __launch_bounds__(1024) void kA_scatter(const int* __restrict__ src,
                                                   const int* __restrict__ dst,
                                                   const float* __restrict__ h,
                                                   const float* __restrict__ W1,
                                                   const float* __restrict__ W2,
                                                   unsigned int* __restrict__ ebuf,
                                                   int* __restrict__ runoff,
                                                   unsigned short* __restrict__ w1t,
                                                   unsigned short* __restrict__ w2t,
                                                   unsigned short* __restrict__ xb,
                                                   unsigned short* __restrict__ hb,
                                                   int* __restrict__ statsbar) {
    __shared__ int hist[NBUCK];
    __shared__ int ebase[NBUCK];
    __shared__ int sc[512];
    __shared__ unsigned int stage[SCHUNK];
    const int t = threadIdx.x;
    const int e0 = blockIdx.x * SCHUNK;
    const int n = SCHUNK;                         // exact partition

    for (int i = t; i < NBUCK; i += 1024) hist[i] = 0;
    __syncthreads();
    for (int i = t; i < n; i += 1024)
        atomicAdd(&hist[dst[e0 + i] >> 8], 1);    // int LDS atomic: native ds op
    __syncthreads();

    if (t < 512) sc[t] = (t < NBUCK) ? hist[t] : 0;
    __syncthreads();
    for (int off = 1; off < 512; off <<= 1) {
        int add = (t < 512 && t >= off) ? sc[t - off] : 0;
        __syncthreads();
        if (t < 512) sc[t] += add;
        __syncthreads();
    }
    if (t < NBUCK) {
        int ex = sc[t] - hist[t];
        ebase[t] = ex;
        runoff[blockIdx.x * RSTRIDE + t] = ex;
    }
    if (t == 0) runoff[blockIdx.x * RSTRIDE + NBUCK] = n;
    if (t < NBUCK) hist[t] = 0;
    __syncthreads();

    for (int i = t; i < n; i += 1024) {
        int d = dst[e0 + i];
        int s = src[e0 + i];
        int b = d >> 8;
        int r = atomicAdd(&hist[b], 1);
        stage[ebase[b] + r] = ((unsigned int)s << 8) | (unsigned int)(d & 255);
    }
    __syncthreads();
    for (int i = t; i < n; i += 1024)
        ebuf[e0 + i] = stage[i];

    // ---- fused prep epilogue (no LDS, no barriers needed) ----
    for (int i = blockIdx.x * 1024 + t; i < 800000; i += SBLK * 1024) {
        int e = i * 8;
        float4 f0 = *(const float4*)&h[e];
        float4 f1 = *(const float4*)&h[e + 4];
        uint4 o;
        o.x = pk2(f0.x, f0.y);
        o.y = pk2(f0.z, f0.w);
        o.z = pk2(f1.x, f1.y);
        o.w = pk2(f1.z, f1.w);
        *(uint4*)&hb[e] = o;
    }
    int id = blockIdx.x * 1024 + t;
    if (id < 16384) {                            // w1t: n*64+k
        int nn = id >> 6, k = id & 63;
        int dstp = (nn << 6) + ((((k >> 3) ^ (nn & 7))) << 3) + (k & 7);
        w1t[dstp] = f2bf(W1[k * 256 + nn]);
    } else if (id < 32768) {                     // w2t: d*256+k2
        int i2 = id - 16384;
        int d = i2 >> 8, k2 = i2 & 255;
        int dstp = (d << 8) + ((((k2 >> 3) ^ (d & 7))) << 3) + (k2 & 7);
        w2t[dstp] = f2bf(W2[k2 * 64 + d]);
    } else if (id < 34816) {                     // zero 32 pad rows of xb
        xb[100000 * 64 + (id - 32768)] = 0;
    }
    if (blockIdx.x == 34 && t < 256) statsbar[t] = 0;
}

// ---------------------------------------------------------------------------
// Pass B (fused, register-accumulate): one block per bucket.
// 1) 2-threads-per-run copy of bucket edges -> stage2 (LDS) + degree histogram
// 2) per-node offsets via LDS scan; sort src ids into sout (int LDS atomics)
// 3) 8-lane group per node: walk contiguous sout segment with 4-edge-deep
//    prefetch pipeline (4 global_load_dwordx4 in flight), register-accumulate,
//    emit xb row (swizzled bf16).
// ---------------------------------------------------------------------------
#define ACC8(v)                                                                 \
    do {                                                                        \
        a0 += __uint_as_float((v).x << 16);                                     \
        a1 += __uint_as_float((v).x & 0xffff0000u);                             \
        a2 += __uint_as_float((v).y << 16);                                     \
        a3 += __uint_as_float((v).y & 0xffff0000u);                             \
        a4 += __uint_as_float((v).z << 16);                                     \
        a5 += __uint_as_float((v).z & 0xffff0000u);                             \
        a6 += __uint_as_float((v).w << 16);                                     \
        a7 += __uint_as_float((v).w & 0xffff0000u);                             \
    } while (0)

__global__ __launch_bounds__(1024) void kB_fused(const unsigned int* __restrict__ ebuf,
                                                 const int* __restrict__ runoff,
                                                 const unsigned short* __restrict__ hb,
                                                 unsigned short* __restrict__ xb) {
    __shared__ int runstart_s[SBLK];
    __shared__ int sc[SBLK];
    __shared__ int cnt[256];
    __shared__ int off[256];
    __shared__ unsigned int stage2[MAXB];
    __shared__ unsigned int sout[MAXB];
    const int t = threadIdx.x;
    const int b = blockIdx.x;

    int rl = 0;
    if (t < SBLK) {
        int s = runoff[t * RSTRIDE + b];
        int e = runoff[t * RSTRIDE + b + 1];
        runstart_s[t] = t * SCHUNK + s;
        rl = e - s;
        sc[t] = rl;
    }
    if (t < 256) cnt[t] = 0;
    __syncthreads();
    for (int o = 1; o < SBLK; o <<= 1) {
        int add = (t < SBLK && t >= o) ? sc[t - o] : 0;
        __syncthreads();
        if (t < SBLK) sc[t] += add;
        __syncthreads();
    }
    const int total = min(sc[SBLK - 1], MAXB);
    __syncthreads();

    // copy into LDS: two threads per run (front half / back half) + histogram
    {
        const int r = t & 511;
        const int hf = t >> 9;
        int prev = (r == 0) ? 0 : sc[r - 1];
        int rlr = sc[r] - prev;
        int h0 = (rlr + 1) >> 1;
        int st = hf ? h0 : 0;
        int en = hf ? rlr : h0;
        int rs0 = runstart_s[r];
        for (int k = st; k < en; ++k) {
            int pos = prev + k;
            if (pos >= MAXB) break;
            unsigned int v = ebuf[rs0 + k];
            stage2[pos] = v;
            atomicAdd(&cnt[v & 255u], 1);
        }
    }
    __syncthreads();

    // per-node exclusive offsets within the bucket
    int c0s = (t < 256) ? cnt[t] : 0;
    if (t < 256) sc[t] = c0s;
    __syncthreads();
    for (int o = 1; o < 256; o <<= 1) {
        int add = (t < 256 && t >= o) ? sc[t - o] : 0;
        __syncthreads();
        if (t < 256) sc[t] += add;
        __syncthreads();
    }
    if (t < 256) { off[t] = sc[t] - c0s; cnt[t] = 0; }
    __syncthreads();

    // sort src ids by node into sout (contiguous per-node segments)
    for (int idx = t; idx < total; idx += 1024) {
        unsigned int v = stage2[idx];
        int node = (int)(v & 255u);
        int r = atomicAdd(&cnt[node], 1);
        sout[off[node] + r] = v >> 8;
    }
    __syncthreads();

    // aggregate: 8-lane group per node; lane c covers dims c*8..c*8+7.
    const int g = t >> 3, c = t & 7;
    const unsigned short* hc = hb + c * 8;
    const int gn0 = b * 256;
#pragma unroll
    for (int pass = 0; pass < 2; ++pass) {
        int nloc = pass * 128 + g;
        int gnode = gn0 + nloc;
        if (gnode >= N_NODES) continue;
        const int o0 = off[nloc];
        const int dg = cnt[nloc];
        float a0 = 0.f, a1 = 0.f, a2 = 0.f, a3 = 0.f;
        float a4 = 0.f, a5 = 0.f, a6 = 0.f, a7 = 0.f;
        const int nq = dg >> 2;                   // quads of 4 edges
        uint4 p0, p1, p2, p3;
        if (nq > 0) {
            int i0 = (int)sout[o0 + 0];
            int i1 = (int)sout[o0 + 1];
            int i2 = (int)sout[o0 + 2];
            int i3 = (int)sout[o0 + 3];
            p0 = *(const uint4*)&hc[(size_t)i0 * 64];
            p1 = *(const uint4*)&hc[(size_t)i1 * 64];
            p2 = *(const uint4*)&hc[(size_t)i2 * 64];
            p3 = *(const uint4*)&hc[(size_t)i3 * 64];
        }
        for (int q = 0; q < nq; ++q) {
            uint4 c0v = p0, c1v = p1, c2v = p2, c3v = p3;
            int j4 = (q + 1) * 4;
            if (q + 1 < nq) {
                int i0 = (int)sout[o0 + j4 + 0];
                int i1 = (int)sout[o0 + j4 + 1];
                int i2 = (int)sout[o0 + j4 + 2];
                int i3 = (int)sout[o0 + j4 + 3];
                p0 = *(const uint4*)&hc[(size_t)i0 * 64];
                p1 = *(const uint4*)&hc[(size_t)i1 * 64];
                p2 = *(const uint4*)&hc[(size_t)i2 * 64];
                p3 = *(const uint4*)&hc[(size_t)i3 * 64];
            }
            ACC8(c0v);
            ACC8(c1v);
            ACC8(c2v);
            ACC8(c3v);
        }
        for (int j = nq * 4; j < dg; ++j) {       // tail 0..3 edges
            int il = (int)sout[o0 + j];
            uint4 v0 = *(const uint4*)&hc[(size_t)il * 64];
            ACC8(v0);
        }
        const float inv = 1.0f / (float)max(dg, 1);
        uint4 ov = *(const uint4*)&hc[(size_t)gnode * 64];
        float x0 = fmaf(a0, inv, __uint_as_float(ov.x << 16));
        float x1 = fmaf(a1, inv, __uint_as_float(ov.x & 0xffff0000u));
        float x2 = fmaf(a2, inv, __uint_as_float(ov.y << 16));
        float x3 = fmaf(a3, inv, __uint_as_float(ov.y & 0xffff0000u));
        float x4 = fmaf(a4, inv, __uint_as_float(ov.z << 16));
        float x5 = fmaf(a5, inv, __uint_as_float(ov.z & 0xffff0000u));
        float x6 = fmaf(a6, inv, __uint_as_float(ov.w << 16));
        float x7 = fmaf(a7, inv, __uint_as_float(ov.w & 0xffff0000u));
        uint4 o;
        o.x = pk2(x0, x1);
        o.y = pk2(x2, x3);
        o.z = pk2(x4, x5);
        o.w = pk2(x6, x7);
        *(uint4*)&xb[(size_t)gnode * 64 + ((c ^ (gnode & 7)) << 3)] = o;
    }
}

// ---------------------------------------------------------------------------
// Fused MLP core (structure verified at r3)
// ---------------------------------------------------------------------------
__device__ __forceinline__ void mlp_tile(const unsigned short* sXw,
                                         const unsigned short* sW1,
                                         const unsigned short* sW2,
                                         unsigned short* sHw,
                                         const float* sB1,
                                         int l15, int g4, int s7,
                                         f32x4 oacc[4]) {
    bf16x8 xf0 = *(const bf16x8*)&sXw[l15 * 64 + ((g4 ^ s7) << 3)];
    bf16x8 xf1 = *(const bf16x8*)&sXw[l15 * 64 + (((g4 + 4) ^ s7) << 3)];
#pragma unroll
    for (int dt = 0; dt < 4; ++dt) oacc[dt] = (f32x4){0.f, 0.f, 0.f, 0.f};

#pragma unroll
    for (int p = 0; p < 4; ++p) {
#pragma unroll
        for (int nt2 = 0; nt2 < 4; ++nt2) {
            const int n0 = p * 64 + nt2 * 16;
            f32x4 hacc = (f32x4){0.f, 0.f, 0.f, 0.f};
            bf16x8 wf0 = *(const bf16x8*)&sW1[(n0 + l15) * 64 + ((g4 ^ s7) << 3)];
            bf16x8 wf1 = *(const bf16x8*)&sW1[(n0 + l15) * 64 + (((g4 + 4) ^ s7) << 3)];
            hacc = __builtin_amdgcn_mfma_f32_16x16x32_bf16(wf0, xf0, hacc, 0, 0, 0);
            hacc = __builtin_amdgcn_mfma_f32_16x16x32_bf16(wf1, xf1, hacc, 0, 0, 0);
            float4 bq = *(const float4*)&sB1[n0 + g4 * 4];
            unsigned plo = pk2(fmaxf(hacc[0] + bq.x, 0.f),
                               fmaxf(hacc[1] + bq.y, 0.f));
            unsigned phi = pk2(fmaxf(hacc[2] + bq.z, 0.f),
                               fmaxf(hacc[3] + bq.w, 0.f));
            int qh = nt2 * 2 + (g4 >> 1);
            uint2 pk = {plo, phi};
            *(uint2*)&sHw[l15 * 64 + ((qh ^ s7) << 3) + ((g4 & 1) << 2)] = pk;
        }
#pragma unroll
        for (int s2 = 0; s2 < 2; ++s2) {
            bf16x8 a2 = *(const bf16x8*)&sHw[l15 * 64 + (((s2 * 4 + g4) ^ s7) << 3)];
#pragma unroll
            for (int dt = 0; dt < 4; ++dt) {
                int q = p * 8 + s2 * 4 + g4;
                bf16x8 w2f = *(const bf16x8*)&sW2[(dt * 16 + l15) * 256 + ((q ^ s7) << 3)];
                oacc[dt] = __builtin_amdgcn_mfma_f32_16x16x32_bf16(a2, w2f, oacc[dt], 0, 0, 0);
            }
        }
    }
}

// single-pass MLP + BN (grid barrier; 256 blocks x 1024 thr = 1 block/CU,
// 16 waves/CU = 4 waves/SIMD for LDS/MFMA latency hiding).
// LDS: 32K sW1 + 32K sW2 + 32K sH + 32K sX + 1K sB1 = 129 KB.
__global__ __launch_bounds__(1024, 1) void k_mlpf(const unsigned short* __restrict__ xb,
                                                  const unsigned short* __restrict__ w1t,
                                                  const unsigned short* __restrict__ w2t,
                                                  const float* __restrict__ b1,
                                                  const float* __restrict__ b2,
                                                  const float* __restrict__ gamma,
                                                  const float* __restrict__ beta,
                                                  float* __restrict__ stats,
                                                  int* __restrict__ bar,
                                                  float* __restrict__ out,
                                                  float* __restrict__ dump) {
    __shared__ unsigned short sW1[256 * 64];
    __shared__ unsigned short sW2[64 * 256];
    __shared__ unsigned short sH[16][16 * 64];
    __shared__ unsigned short sX[16][16 * 64];
    __shared__ float sB1[256];
    const int t = threadIdx.x;
    const int lane = t & 63;
    const int w = t >> 6;                     // 0..15
    const int l15 = lane & 15;
    const int g4 = lane >> 4;
    const int s7 = l15 & 7;
    const int bid = blockIdx.x;

    for (int i = t; i < 2048; i += 1024)
        *(uint4*)&sW1[i * 8] = *(const uint4*)&w1t[i * 8];
    for (int i = t; i < 2048; i += 1024)
        *(uint4*)&sW2[i * 8] = *(const uint4*)&w2t[i * 8];
    if (t < 256) sB1[t] = b1[t];
    __syncthreads();

    float b2v[4];
#pragma unroll
    for (int dt = 0; dt < 4; ++dt) b2v[dt] = b2[dt * 16 + l15];

    float lsum[4] = {0.f, 0.f, 0.f, 0.f};
    float lsq[4]  = {0.f, 0.f, 0.f, 0.f};
    f32x4 osave[MAXIT][4];

#pragma unroll
    for (int it = 0; it < MAXIT; ++it) {
        int gp = bid + it * MLPGRID;
        int r0c = min(gp * 256 + w * 16, XBROWS - 16);
        stage_issue(xb + (size_t)r0c * 64 + lane * 8, &sX[w][0]);
        WAITV(0);
        __builtin_amdgcn_sched_barrier(0);
        const int row0 = gp * 256 + w * 16;
        if (gp < NT && row0 < XBROWS) {
            f32x4 oacc[4];
            mlp_tile(&sX[w][0], sW1, sW2, &sH[w][0], sB1, l15, g4, s7, oacc);
#pragma unroll
            for (int dt = 0; dt < 4; ++dt) {
#pragma unroll
                for (int r = 0; r < 4; ++r) {
                    float val = fmaxf(oacc[dt][r] + b2v[dt], 0.f);
                    osave[it][dt][r] = val;
                    int mabs = row0 + g4 * 4 + r;
                    if (mabs < N_NODES) {
                        lsum[dt] += val;
                        lsq[dt] += val * val;
                    }
                }
            }
        }
    }

    // block-level stats reduction (reuse sW1 memory: [1024][8] f32 = 32 KB)
    __syncthreads();
    float* sred = (float*)&sW1[0];
#pragma unroll
    for (int dt = 0; dt < 4; ++dt) {
        sred[t * 8 + dt] = lsum[dt];
        sred[t * 8 + 4 + dt] = lsq[dt];
    }
    __syncthreads();
    if (t < 128) {
        int issq = (t >= 64) ? 4 : 0;
        int d = t & 63;
        int dt = d >> 4, dl = d & 15;
        float acc = 0.f;
        for (int i = 0; i < 64; ++i) acc += sred[(dl + 16 * i) * 8 + issq + dt];
        atomicAdd(&stats[(issq ? 64 : 0) + d], acc);
    }

    // software grid barrier (all 256 blocks co-resident: 1 block/CU)
    __syncthreads();
    if (t == 0) {
        __hip_atomic_fetch_add(bar, 1, __ATOMIC_ACQ_REL, __HIP_MEMORY_SCOPE_AGENT);
        while (__hip_atomic_load(bar, __ATOMIC_ACQUIRE, __HIP_MEMORY_SCOPE_AGENT)
               < MLPGRID)
            __builtin_amdgcn_s_sleep(4);
    }
    __syncthreads();

    float scv[4], shv[4];
    const float inv_n = 1.0f / (float)N_NODES;
#pragma unroll
    for (int dt = 0; dt < 4; ++dt) {
        int d = dt * 16 + l15;
        float sm = __hip_atomic_load(&stats[d], __ATOMIC_RELAXED,
                                     __HIP_MEMORY_SCOPE_AGENT);
        float sq = __hip_atomic_load(&stats[64 + d], __ATOMIC_RELAXED,
                                     __HIP_MEMORY_SCOPE_AGENT);
        float m = sm * inv_n;
        float v = sq * inv_n - m * m;
        float sc = gamma[d] * rsqrtf(v + BN_EPS);
        scv[dt] = sc;
        shv[dt] = beta[d] - m * sc;
    }

#pragma unroll
    for (int it = 0; it < MAXIT; ++it) {
        int gp = bid + it * MLPGRID;
        const int row0 = gp * 256 + w * 16;
        if (gp >= NT || row0 >= XBROWS) continue;
        float* sHf = (float*)&sH[w][0];           // [8][64] f32 = 2048 B
#pragma unroll
        for (int hh = 0; hh < 2; ++hh) {
            asm volatile("" ::: "memory");
            if ((g4 >> 1) == hh) {
#pragma unroll
                for (int dt = 0; dt < 4; ++dt) {
#pragma unroll
                    for (int r = 0; r < 4; ++r) {
                        float val = fmaf(osave[it][dt][r], scv[dt], shv[dt]);
                        sHf[((g4 & 1) * 4 + r) * 64 + dt * 16 + l15] = val;
                    }
                }
            }
            asm volatile("" ::: "memory");
#pragma unroll
            for (int j = 0; j < 2; ++j) {
                int rl = j * 4 + (lane >> 4);
                int rg = row0 + hh * 8 + rl;
                float4 v = *(const float4*)&sHf[rl * 64 + (lane & 15) * 4];
                float* dstp = (rg < N_NODES)
                    ? &out[(size_t)rg * 64 + (lane & 15) * 4]
                    : &dump[lane * 4];
                *(float4*)dstp = v;
            }
        }
    }
}

extern "C" void kernel_launch(void* const* d_in, const int* in_sizes, int n_in,
                              void* d_out, int out_size, void* d_ws, size_t ws_size,
                              hipStream_t stream) {
    const float* h     = (const float*)d_in[0];
    const float* W1    = (const float*)d_in[1];
    const float* b1    = (const float*)d_in[2];
    const float* W2    = (const float*)d_in[3];
    const float* b2    = (const float*)d_in[4];
    const float* gamma = (const float*)d_in[5];
    const float* beta  = (const float*)d_in[6];
    const int*   src   = (const int*)d_in[7];
    const int*   dst   = (const int*)d_in[8];

    int* wsi = (int*)d_ws;
    float*          stats    = (float*)wsi;                        // 128
    int*            bar      = wsi + 128;                          // 128
    int*            statsbar = wsi;                                // 256 ints
    int*            runoff   = wsi + 256;                          // 200704
    float*          dump     = (float*)(wsi + 256);                // alias (dead)
    unsigned short* w1t      = (unsigned short*)(wsi + 200960);    // 8192 ints
    unsigned short* w2t      = (unsigned short*)(wsi + 209152);    // 8192 ints
    unsigned short* xb       = (unsigned short*)(wsi + 217344);    // 3201024 ints
    unsigned int*   ebuf     = (unsigned int*)(wsi + 3418368);     // 1600000
    unsigned short* hb       = (unsigned short*)(wsi + 5018368);   // 3200000 ints
    float*          out      = (float*)d_out;

    kA_scatter<<<SBLK, 1024, 0, stream>>>(src, dst, h, W1, W2, ebuf, runoff,
                                          w1t, w2t, xb, hb, statsbar);
    kB_fused<<<NBUCK, 1024, 0, stream>>>(ebuf, runoff, hb, xb);
    k_mlpf<<<MLPGRID, 1024, 0, stream>>>(xb, w1t, w2t, b1, b2, gamma, beta,
                                         stats, bar, out, dump);
}